// Round 1
// baseline (2999.428 us; speedup 1.0000x reference)
//
#include <hip/hip_runtime.h>
#include <hip/hip_bf16.h>
#include <math.h>

#define N_TOK 8192
#define DDIM  1024
#define HDIM  4096
#define NBLK  512
#define KSEL  8

__device__ __forceinline__ float wave_reduce_sum(float v) {
#pragma unroll
    for (int off = 32; off > 0; off >>= 1) v += __shfl_down(v, off, 64);
    return v;
}

// ---------------------------------------------------------------------------
// Normalize rows of raw_U / raw_V: unit = row / max(||row||, 1e-6)
// grid = 2*NBLK blocks, 256 threads
// ---------------------------------------------------------------------------
__global__ void norm_rows_kernel(const float* __restrict__ rawU,
                                 const float* __restrict__ rawV,
                                 float* __restrict__ unitU,
                                 float* __restrict__ unitV) {
    int b = blockIdx.x;
    const float* src = (b < NBLK) ? rawU + (size_t)b * DDIM
                                  : rawV + (size_t)(b - NBLK) * DDIM;
    float* dst = (b < NBLK) ? unitU + (size_t)b * DDIM
                            : unitV + (size_t)(b - NBLK) * DDIM;
    int t = threadIdx.x;
    float vals[4];
    float ss = 0.f;
#pragma unroll
    for (int i = 0; i < 4; i++) { vals[i] = src[t + i * 256]; ss += vals[i] * vals[i]; }
    __shared__ float red[4];
    ss = wave_reduce_sum(ss);
    if ((t & 63) == 0) red[t >> 6] = ss;
    __syncthreads();
    float tot = red[0] + red[1] + red[2] + red[3];
    float inv = 1.f / fmaxf(sqrtf(tot), 1e-6f);
#pragma unroll
    for (int i = 0; i < 4; i++) dst[t + i * 256] = vals[i] * inv;
}

// ---------------------------------------------------------------------------
// LayerNorm rows of x -> ln_x. grid = N_TOK blocks, 256 threads
// ---------------------------------------------------------------------------
__global__ void ln_kernel(const float* __restrict__ x,
                          const float* __restrict__ g,
                          const float* __restrict__ bb,
                          float* __restrict__ ln_x) {
    int n = blockIdx.x;
    int t = threadIdx.x;
    const float* row = x + (size_t)n * DDIM;
    float v[4];
    float s1 = 0.f, s2 = 0.f;
#pragma unroll
    for (int i = 0; i < 4; i++) {
        v[i] = row[t + i * 256];
        s1 += v[i];
        s2 += v[i] * v[i];
    }
    __shared__ float r1[4], r2[4];
    s1 = wave_reduce_sum(s1);
    s2 = wave_reduce_sum(s2);
    if ((t & 63) == 0) { r1[t >> 6] = s1; r2[t >> 6] = s2; }
    __syncthreads();
    float mu  = (r1[0] + r1[1] + r1[2] + r1[3]) * (1.f / DDIM);
    float var = (r2[0] + r2[1] + r2[2] + r2[3]) * (1.f / DDIM) - mu * mu;
    float rstd = rsqrtf(var + 1e-5f);
    float* orow = ln_x + (size_t)n * DDIM;
#pragma unroll
    for (int i = 0; i < 4; i++) {
        int d = t + i * 256;
        orow[d] = (v[i] - mu) * rstd * g[d] + bb[d];
    }
}

// ---------------------------------------------------------------------------
// Tiled NT GEMM: C[M,Nn] = A[M,Kk] * B[Nn,Kk]^T  (+ epilogue per MODE)
//   MODE 0: A fp32; epi = softplus(clip(acc + bias)) -> fp32   (router)
//   MODE 1: A fp32; epi = gelu_exact(acc) -> bf16              (gemm1)
//   MODE 2: A bf16; epi = C += acc (fp32 read-modify-write)    (gemm2)
// BM=BN=64, BK=16, 256 threads, 4x4 micro-tile per thread
// ---------------------------------------------------------------------------
template <int MODE>
__global__ __launch_bounds__(256) void gemm_nt(const void* __restrict__ Av,
                                               const float* __restrict__ Bmat,
                                               const float* __restrict__ bias,
                                               void* __restrict__ Cv,
                                               int M, int Nn, int Kk) {
    __shared__ float As[64][17];
    __shared__ float Bs[64][17];
    const int t  = threadIdx.x;
    const int m0 = blockIdx.x * 64;
    const int n0 = blockIdx.y * 64;
    const int lr = t >> 2;          // 0..63 row within tile for loads
    const int lc = (t & 3) << 2;    // 0,4,8,12 k-offset for loads
    const int tx = t & 15, ty = t >> 4;

    float acc[4][4];
#pragma unroll
    for (int i = 0; i < 4; i++)
#pragma unroll
        for (int j = 0; j < 4; j++) acc[i][j] = 0.f;

    for (int k0 = 0; k0 < Kk; k0 += 16) {
        if (MODE == 2) {
            const __hip_bfloat16* A = (const __hip_bfloat16*)Av;
            const __hip_bfloat16* p = A + (size_t)(m0 + lr) * Kk + k0 + lc;
#pragma unroll
            for (int i = 0; i < 4; i++) As[lr][lc + i] = __bfloat162float(p[i]);
        } else {
            const float* A = (const float*)Av;
            const float4 v = *(const float4*)(A + (size_t)(m0 + lr) * Kk + k0 + lc);
            As[lr][lc + 0] = v.x; As[lr][lc + 1] = v.y;
            As[lr][lc + 2] = v.z; As[lr][lc + 3] = v.w;
        }
        {
            const float4 v = *(const float4*)(Bmat + (size_t)(n0 + lr) * Kk + k0 + lc);
            Bs[lr][lc + 0] = v.x; Bs[lr][lc + 1] = v.y;
            Bs[lr][lc + 2] = v.z; Bs[lr][lc + 3] = v.w;
        }
        __syncthreads();
#pragma unroll
        for (int kk = 0; kk < 16; kk++) {
            float a[4], b[4];
#pragma unroll
            for (int i = 0; i < 4; i++) a[i] = As[ty * 4 + i][kk];
#pragma unroll
            for (int j = 0; j < 4; j++) b[j] = Bs[tx * 4 + j][kk];
#pragma unroll
            for (int i = 0; i < 4; i++)
#pragma unroll
                for (int j = 0; j < 4; j++) acc[i][j] = fmaf(a[i], b[j], acc[i][j]);
        }
        __syncthreads();
    }

#pragma unroll
    for (int i = 0; i < 4; i++) {
        int m = m0 + ty * 4 + i;
#pragma unroll
        for (int j = 0; j < 4; j++) {
            int nn = n0 + tx * 4 + j;
            float v = acc[i][j];
            if (MODE == 0) {
                float r = v + bias[nn];
                r = fminf(fmaxf(r, -10.f), 10.f);
                ((float*)Cv)[(size_t)m * Nn + nn] = log1pf(expf(r));
            } else if (MODE == 1) {
                float gg = 0.5f * v * (1.f + erff(v * 0.7071067811865476f));
                ((__hip_bfloat16*)Cv)[(size_t)m * Nn + nn] = __float2bfloat16(gg);
            } else {
                ((float*)Cv)[(size_t)m * Nn + nn] += v;
            }
        }
    }
}

// ---------------------------------------------------------------------------
// Top-8 of alpha[n, 0..511] per token; one wave per token (4 tokens/block).
// Writes idx [N,8] and Z [N,8] where Z = phi/(S+1e-6)*tanh(S).
// ---------------------------------------------------------------------------
__global__ void topk_kernel(const float* __restrict__ alpha,
                            int* __restrict__ idx_out,
                            float* __restrict__ z_out) {
    int n    = blockIdx.x * 4 + (threadIdx.x >> 6);
    int lane = threadIdx.x & 63;
    const float* row = alpha + (size_t)n * NBLK;
    float v[8];
#pragma unroll
    for (int i = 0; i < 8; i++) v[i] = row[lane + i * 64];

    float topv[8];
    int   topi[8];
    for (int s = 0; s < 8; s++) {
        float bv = v[0]; int bi = 0;
#pragma unroll
        for (int i = 1; i < 8; i++)
            if (v[i] > bv) { bv = v[i]; bi = i; }
        int gidx = lane + bi * 64;
#pragma unroll
        for (int off = 1; off < 64; off <<= 1) {
            float ov = __shfl_xor(bv, off, 64);
            int   oi = __shfl_xor(gidx, off, 64);
            if (ov > bv || (ov == bv && oi < gidx)) { bv = ov; gidx = oi; }
        }
        topv[s] = bv; topi[s] = gidx;
        if ((gidx & 63) == lane) v[gidx >> 6] = -1e30f;  // remove winner
    }
    float S = 0.f;
#pragma unroll
    for (int s = 0; s < 8; s++) S += topv[s];
    float zscale = tanhf(S) / (S + 1e-6f);
    if (lane < 8) {
        idx_out[(size_t)n * 8 + lane] = topi[lane];
        z_out[(size_t)n * 8 + lane]   = topv[lane] * zscale;
    }
}

// ---------------------------------------------------------------------------
// Dynamic path: h_lat_k = x_n . unitU[idx_k]; out_n = gamma * sum_k
// (h_lat_k * Z_k) * unitV[idx_k].  One block per token. Writes out (overwrite).
// ---------------------------------------------------------------------------
__global__ void dyn_kernel(const float* __restrict__ x,
                           const float* __restrict__ unitU,
                           const float* __restrict__ unitV,
                           const int* __restrict__ idx,
                           const float* __restrict__ Z,
                           const float* __restrict__ gamma,
                           float* __restrict__ out) {
    int n = blockIdx.x;
    int t = threadIdx.x;
    __shared__ int   sidx[8];
    __shared__ float shz[8];
    __shared__ float red[8][4];
    __shared__ float hz[8];
    if (t < 8) { sidx[t] = idx[(size_t)n * 8 + t]; shz[t] = Z[(size_t)n * 8 + t]; }
    __syncthreads();

    const float* xr = x + (size_t)n * DDIM;
    float xv[4];
#pragma unroll
    for (int i = 0; i < 4; i++) xv[i] = xr[t + i * 256];

    float acc[8];
#pragma unroll
    for (int k = 0; k < 8; k++) {
        const float* ur = unitU + (size_t)sidx[k] * DDIM;
        float a = 0.f;
#pragma unroll
        for (int i = 0; i < 4; i++) a = fmaf(xv[i], ur[t + i * 256], a);
        acc[k] = a;
    }
    int wid = t >> 6, lane = t & 63;
#pragma unroll
    for (int k = 0; k < 8; k++) {
        float a = wave_reduce_sum(acc[k]);
        if (lane == 0) red[k][wid] = a;
    }
    __syncthreads();
    if (t < 8) {
        float h = red[t][0] + red[t][1] + red[t][2] + red[t][3];
        hz[t] = h * shz[t];
    }
    __syncthreads();

    float* orow = out + (size_t)n * DDIM;
#pragma unroll
    for (int i = 0; i < 4; i++) {
        int d = t + i * 256;
        float s = 0.f;
#pragma unroll
        for (int k = 0; k < 8; k++)
            s = fmaf(hz[k], unitV[(size_t)sidx[k] * DDIM + d], s);
        orow[d] = s * gamma[d];
    }
}

// ---------------------------------------------------------------------------
extern "C" void kernel_launch(void* const* d_in, const int* in_sizes, int n_in,
                              void* d_out, int out_size, void* d_ws, size_t ws_size,
                              hipStream_t stream) {
    const float* x        = (const float*)d_in[0];
    const float* W1       = (const float*)d_in[1];
    const float* W2       = (const float*)d_in[2];
    const float* ln_g     = (const float*)d_in[3];
    const float* ln_b     = (const float*)d_in[4];
    const float* router_W = (const float*)d_in[5];
    const float* router_b = (const float*)d_in[6];
    const float* raw_U    = (const float*)d_in[7];
    const float* raw_V    = (const float*)d_in[8];
    const float* gamma    = (const float*)d_in[9];
    float* out = (float*)d_out;

    char* ws = (char*)d_ws;
    float*          ln_x  = (float*)(ws);                      // 33,554,432 B
    float*          alpha = (float*)(ws + 33554432u);          // 16,777,216 B
    __hip_bfloat16* g1    = (__hip_bfloat16*)(ws + 50331648u); // 67,108,864 B
    float*          unitU = (float*)(ws + 117440512u);         //  2,097,152 B
    float*          unitV = (float*)(ws + 119537664u);         //  2,097,152 B
    int*            idx   = (int*)(ws + 121634816u);           //    262,144 B
    float*          Zbuf  = (float*)(ws + 121896960u);         //    262,144 B
    // total ws use: 122,159,104 B

    norm_rows_kernel<<<2 * NBLK, 256, 0, stream>>>(raw_U, raw_V, unitU, unitV);
    ln_kernel<<<N_TOK, 256, 0, stream>>>(x, ln_g, ln_b, ln_x);

    dim3 gR(N_TOK / 64, NBLK / 64);
    gemm_nt<0><<<gR, 256, 0, stream>>>((const void*)ln_x, router_W, router_b,
                                       (void*)alpha, N_TOK, NBLK, DDIM);

    topk_kernel<<<N_TOK / 4, 256, 0, stream>>>(alpha, idx, Zbuf);
    dyn_kernel<<<N_TOK, 256, 0, stream>>>(x, unitU, unitV, idx, Zbuf, gamma, out);

    dim3 g1d(N_TOK / 64, HDIM / 64);
    gemm_nt<1><<<g1d, 256, 0, stream>>>((const void*)x, W1, nullptr,
                                        (void*)g1, N_TOK, HDIM, DDIM);

    dim3 g2d(N_TOK / 64, DDIM / 64);
    gemm_nt<2><<<g2d, 256, 0, stream>>>((const void*)g1, W2, nullptr,
                                        (void*)out, N_TOK, DDIM, HDIM);
}

// Round 3
// 584.867 us; speedup vs baseline: 5.1284x; 5.1284x over previous
//
#include <hip/hip_runtime.h>
#include <hip/hip_bf16.h>
#include <math.h>

#define N_TOK 8192
#define DDIM  1024
#define HDIM  4096
#define NBLK  512

typedef __bf16 bf16x8 __attribute__((ext_vector_type(8)));
typedef __bf16 bf16x4 __attribute__((ext_vector_type(4)));
typedef float  floatx4 __attribute__((ext_vector_type(4)));

__device__ __forceinline__ float wave_reduce_sum(float v) {
#pragma unroll
    for (int off = 32; off > 0; off >>= 1) v += __shfl_down(v, off, 64);
    return v;
}

__device__ __forceinline__ void gload_lds16(const void* g, void* l) {
    __builtin_amdgcn_global_load_lds((const __attribute__((address_space(1))) void*)g,
                                     (__attribute__((address_space(3))) void*)l,
                                     16, 0, 0);
}

// ---------------------------------------------------------------------------
// fp32 -> bf16 cast, 4 elems/thread
// ---------------------------------------------------------------------------
__global__ void cast_bf16_kernel(const float* __restrict__ s,
                                 __bf16* __restrict__ d, int n4) {
    int i = blockIdx.x * 256 + threadIdx.x;
    if (i < n4) {
        float4 v = ((const float4*)s)[i];
        bf16x4 o;
        o.x = (__bf16)v.x; o.y = (__bf16)v.y;
        o.z = (__bf16)v.z; o.w = (__bf16)v.w;
        ((bf16x4*)d)[i] = o;
    }
}

// ---------------------------------------------------------------------------
// Normalize rows of raw_U / raw_V
// ---------------------------------------------------------------------------
__global__ void norm_rows_kernel(const float* __restrict__ rawU,
                                 const float* __restrict__ rawV,
                                 float* __restrict__ unitU,
                                 float* __restrict__ unitV) {
    int b = blockIdx.x;
    const float* src = (b < NBLK) ? rawU + (size_t)b * DDIM
                                  : rawV + (size_t)(b - NBLK) * DDIM;
    float* dst = (b < NBLK) ? unitU + (size_t)b * DDIM
                            : unitV + (size_t)(b - NBLK) * DDIM;
    int t = threadIdx.x;
    float vals[4];
    float ss = 0.f;
#pragma unroll
    for (int i = 0; i < 4; i++) { vals[i] = src[t + i * 256]; ss += vals[i] * vals[i]; }
    __shared__ float red[4];
    ss = wave_reduce_sum(ss);
    if ((t & 63) == 0) red[t >> 6] = ss;
    __syncthreads();
    float tot = red[0] + red[1] + red[2] + red[3];
    float inv = 1.f / fmaxf(sqrtf(tot), 1e-6f);
#pragma unroll
    for (int i = 0; i < 4; i++) dst[t + i * 256] = vals[i] * inv;
}

// ---------------------------------------------------------------------------
// LayerNorm rows of x -> bf16 ln_x
// ---------------------------------------------------------------------------
__global__ void ln_kernel(const float* __restrict__ x,
                          const float* __restrict__ g,
                          const float* __restrict__ bb,
                          __bf16* __restrict__ ln_x) {
    int n = blockIdx.x;
    int t = threadIdx.x;
    const float* row = x + (size_t)n * DDIM;
    float v[4];
    float s1 = 0.f, s2 = 0.f;
#pragma unroll
    for (int i = 0; i < 4; i++) {
        v[i] = row[t + i * 256];
        s1 += v[i];
        s2 += v[i] * v[i];
    }
    __shared__ float r1[4], r2[4];
    s1 = wave_reduce_sum(s1);
    s2 = wave_reduce_sum(s2);
    if ((t & 63) == 0) { r1[t >> 6] = s1; r2[t >> 6] = s2; }
    __syncthreads();
    float mu  = (r1[0] + r1[1] + r1[2] + r1[3]) * (1.f / DDIM);
    float var = (r2[0] + r2[1] + r2[2] + r2[3]) * (1.f / DDIM) - mu * mu;
    float rstd = rsqrtf(var + 1e-5f);
    __bf16* orow = ln_x + (size_t)n * DDIM;
#pragma unroll
    for (int i = 0; i < 4; i++) {
        int d = t + i * 256;
        orow[d] = (__bf16)((v[i] - mu) * rstd * g[d] + bb[d]);
    }
}

// ---------------------------------------------------------------------------
// bf16 MFMA NT GEMM: C[M,Nn] = A[M,Kk] (bf16) * B[Nn,Kk]^T (bf16)
// 128x128 tile, BK=32, 256 threads (4 waves, 2x2 of 64x64), 16x16x32 MFMA.
// MODE 0: D = softplus(clip(acc+bias)) -> fp32      (router)
// MODE 1: D = gelu_exact(acc) -> bf16               (gemm1)
// MODE 2: C += acc (fp32 rmw)                       (gemm2)
// ---------------------------------------------------------------------------
template <int MODE>
__global__ __launch_bounds__(256) void mfma_gemm(const __bf16* __restrict__ A,
                                                 const __bf16* __restrict__ B,
                                                 const float* __restrict__ bias,
                                                 void* __restrict__ Cv,
                                                 int M, int Nn, int Kk) {
    __shared__ __align__(16) __bf16 As[128 * 32];
    __shared__ __align__(16) __bf16 Bs[128 * 32];

    const int t    = threadIdx.x;
    const int lane = t & 63;
    const int wave = t >> 6;
    const int wm   = wave >> 1, wn = wave & 1;
    const int lr   = lane & 15, quad = lane >> 4;
    const int m0   = blockIdx.x * 128;
    const int n0   = blockIdx.y * 128;

    // staging: idx = i*256 + t; row = idx>>2, chunk = idx&3 (8 bf16 per chunk)
    const int ma0 = t >> 2,         ca0 = t & 3;
    const int ma1 = (256 + t) >> 2;
    const __bf16* Ag0 = A + (size_t)(m0 + ma0) * Kk + ca0 * 8;
    const __bf16* Ag1 = A + (size_t)(m0 + ma1) * Kk + ca0 * 8;
    const __bf16* Bg0 = B + (size_t)(n0 + ma0) * Kk + ca0 * 8;
    const __bf16* Bg1 = B + (size_t)(n0 + ma1) * Kk + ca0 * 8;
    __bf16* ldsA0 = As + t * 8;
    __bf16* ldsA1 = As + (256 + t) * 8;
    __bf16* ldsB0 = Bs + t * 8;
    __bf16* ldsB1 = Bs + (256 + t) * 8;

    // LDS read pointers for fragments
    const __bf16* ra[4];
    const __bf16* rb[4];
#pragma unroll
    for (int i = 0; i < 4; i++) {
        ra[i] = As + (wm * 64 + i * 16 + lr) * 32 + quad * 8;
        rb[i] = Bs + (wn * 64 + i * 16 + lr) * 32 + quad * 8;
    }

    floatx4 acc[4][4];
#pragma unroll
    for (int i = 0; i < 4; i++)
#pragma unroll
        for (int j = 0; j < 4; j++) acc[i][j] = (floatx4)0.f;

    for (int k0 = 0; k0 < Kk; k0 += 32) {
        gload_lds16(Ag0 + k0, ldsA0);
        gload_lds16(Ag1 + k0, ldsA1);
        gload_lds16(Bg0 + k0, ldsB0);
        gload_lds16(Bg1 + k0, ldsB1);
        __syncthreads();

        bf16x8 af[4], bfr[4];
#pragma unroll
        for (int i = 0; i < 4; i++) af[i]  = *(const bf16x8*)ra[i];
#pragma unroll
        for (int j = 0; j < 4; j++) bfr[j] = *(const bf16x8*)rb[j];
#pragma unroll
        for (int i = 0; i < 4; i++)
#pragma unroll
            for (int j = 0; j < 4; j++)
                acc[i][j] = __builtin_amdgcn_mfma_f32_16x16x32_bf16(af[i], bfr[j],
                                                                    acc[i][j], 0, 0, 0);
        __syncthreads();
    }

    // Epilogue. D(lane, reg r) = C[quad*4 + r][lr] per 16x16 tile.
    const int mBase = m0 + wm * 64 + quad * 4;
    const int nBase = n0 + wn * 64 + lr;
#pragma unroll
    for (int i = 0; i < 4; i++) {
#pragma unroll
        for (int j = 0; j < 4; j++) {
            int n = nBase + j * 16;
#pragma unroll
            for (int r = 0; r < 4; r++) {
                int m = mBase + i * 16 + r;
                float v = acc[i][j][r];
                if (MODE == 0) {
                    float rr = v + bias[n];
                    rr = fminf(fmaxf(rr, -10.f), 10.f);
                    ((float*)Cv)[(size_t)m * Nn + n] = log1pf(expf(rr));
                } else if (MODE == 1) {
                    float gg = 0.5f * v * (1.f + erff(v * 0.7071067811865476f));
                    ((__bf16*)Cv)[(size_t)m * Nn + n] = (__bf16)gg;
                } else {
                    ((float*)Cv)[(size_t)m * Nn + n] += v;
                }
            }
        }
    }
}

// ---------------------------------------------------------------------------
// Top-8 per token; one wave per token (4 tokens/block).
// ---------------------------------------------------------------------------
__global__ void topk_kernel(const float* __restrict__ alpha,
                            int* __restrict__ idx_out,
                            float* __restrict__ z_out) {
    int n    = blockIdx.x * 4 + (threadIdx.x >> 6);
    int lane = threadIdx.x & 63;
    const float* row = alpha + (size_t)n * NBLK;
    float v[8];
#pragma unroll
    for (int i = 0; i < 8; i++) v[i] = row[lane + i * 64];

    float topv[8];
    int   topi[8];
    for (int s = 0; s < 8; s++) {
        float bv = v[0]; int bi = 0;
#pragma unroll
        for (int i = 1; i < 8; i++)
            if (v[i] > bv) { bv = v[i]; bi = i; }
        int gidx = lane + bi * 64;
#pragma unroll
        for (int off = 1; off < 64; off <<= 1) {
            float ov = __shfl_xor(bv, off, 64);
            int   oi = __shfl_xor(gidx, off, 64);
            if (ov > bv || (ov == bv && oi < gidx)) { bv = ov; gidx = oi; }
        }
        topv[s] = bv; topi[s] = gidx;
        if ((gidx & 63) == lane) v[gidx >> 6] = -1e30f;
    }
    float S = 0.f;
#pragma unroll
    for (int s = 0; s < 8; s++) S += topv[s];
    float zscale = tanhf(S) / (S + 1e-6f);
    if (lane < 8) {
        idx_out[(size_t)n * 8 + lane] = topi[lane];
        z_out[(size_t)n * 8 + lane]   = topv[lane] * zscale;
    }
}

// ---------------------------------------------------------------------------
// Dynamic path (overwrites out)
// ---------------------------------------------------------------------------
__global__ void dyn_kernel(const float* __restrict__ x,
                           const float* __restrict__ unitU,
                           const float* __restrict__ unitV,
                           const int* __restrict__ idx,
                           const float* __restrict__ Z,
                           const float* __restrict__ gamma,
                           float* __restrict__ out) {
    int n = blockIdx.x;
    int t = threadIdx.x;
    __shared__ int   sidx[8];
    __shared__ float shz[8];
    __shared__ float red[8][4];
    __shared__ float hz[8];
    if (t < 8) { sidx[t] = idx[(size_t)n * 8 + t]; shz[t] = Z[(size_t)n * 8 + t]; }
    __syncthreads();

    const float* xr = x + (size_t)n * DDIM;
    float xv[4];
#pragma unroll
    for (int i = 0; i < 4; i++) xv[i] = xr[t + i * 256];

    float acc[8];
#pragma unroll
    for (int k = 0; k < 8; k++) {
        const float* ur = unitU + (size_t)sidx[k] * DDIM;
        float a = 0.f;
#pragma unroll
        for (int i = 0; i < 4; i++) a = fmaf(xv[i], ur[t + i * 256], a);
        acc[k] = a;
    }
    int wid = t >> 6, lane = t & 63;
#pragma unroll
    for (int k = 0; k < 8; k++) {
        float a = wave_reduce_sum(acc[k]);
        if (lane == 0) red[k][wid] = a;
    }
    __syncthreads();
    if (t < 8) {
        float h = red[t][0] + red[t][1] + red[t][2] + red[t][3];
        hz[t] = h * shz[t];
    }
    __syncthreads();

    float* orow = out + (size_t)n * DDIM;
#pragma unroll
    for (int i = 0; i < 4; i++) {
        int d = t + i * 256;
        float s = 0.f;
#pragma unroll
        for (int k = 0; k < 8; k++)
            s = fmaf(hz[k], unitV[(size_t)sidx[k] * DDIM + d], s);
        orow[d] = s * gamma[d];
    }
}

// ---------------------------------------------------------------------------
extern "C" void kernel_launch(void* const* d_in, const int* in_sizes, int n_in,
                              void* d_out, int out_size, void* d_ws, size_t ws_size,
                              hipStream_t stream) {
    const float* x        = (const float*)d_in[0];
    const float* W1       = (const float*)d_in[1];
    const float* W2       = (const float*)d_in[2];
    const float* ln_g     = (const float*)d_in[3];
    const float* ln_b     = (const float*)d_in[4];
    const float* router_W = (const float*)d_in[5];
    const float* router_b = (const float*)d_in[6];
    const float* raw_U    = (const float*)d_in[7];
    const float* raw_V    = (const float*)d_in[8];
    const float* gamma    = (const float*)d_in[9];
    float* out = (float*)d_out;

    char* ws = (char*)d_ws;
    // region [0, 67.1MB): lnb+alpha early, g1 later (dead/live ranges disjoint)
    __bf16* lnb   = (__bf16*)(ws);                 // 16,777,216 B
    float*  alpha = (float*)(ws + 16777216u);      // 16,777,216 B
    __bf16* g1    = (__bf16*)(ws);                 // 67,108,864 B (after topk)
    __bf16* xb    = (__bf16*)(ws + 67108864u);     // 16,777,216 B
    __bf16* w1b   = (__bf16*)(ws + 83886080u);     //  8,388,608 B
    __bf16* w2b   = (__bf16*)(ws + 92274688u);     //  8,388,608 B
    __bf16* rwb   = (__bf16*)(ws + 100663296u);    //  1,048,576 B
    float*  unitU = (float*)(ws + 101711872u);     //  2,097,152 B
    float*  unitV = (float*)(ws + 103809024u);     //  2,097,152 B
    int*    idx   = (int*)(ws + 105906176u);       //    262,144 B
    float*  Zbuf  = (float*)(ws + 106168320u);     //    262,144 B
    // total ws use: 106,430,464 B

    // bf16 casts
    cast_bf16_kernel<<<(N_TOK * DDIM / 4 + 255) / 256, 256, 0, stream>>>(x, xb, N_TOK * DDIM / 4);
    cast_bf16_kernel<<<(HDIM * DDIM / 4 + 255) / 256, 256, 0, stream>>>(W1, w1b, HDIM * DDIM / 4);
    cast_bf16_kernel<<<(DDIM * HDIM / 4 + 255) / 256, 256, 0, stream>>>(W2, w2b, DDIM * HDIM / 4);
    cast_bf16_kernel<<<(NBLK * DDIM / 4 + 255) / 256, 256, 0, stream>>>(router_W, rwb, NBLK * DDIM / 4);

    norm_rows_kernel<<<2 * NBLK, 256, 0, stream>>>(raw_U, raw_V, unitU, unitV);
    ln_kernel<<<N_TOK, 256, 0, stream>>>(x, ln_g, ln_b, lnb);

    // router: [8192,512] = lnb @ rwb^T, softplus epilogue
    dim3 gR(N_TOK / 128, NBLK / 128);
    mfma_gemm<0><<<gR, 256, 0, stream>>>(lnb, rwb, router_b, (void*)alpha, N_TOK, NBLK, DDIM);

    topk_kernel<<<N_TOK / 4, 256, 0, stream>>>(alpha, idx, Zbuf);
    dyn_kernel<<<N_TOK, 256, 0, stream>>>(x, unitU, unitV, idx, Zbuf, gamma, out);

    // gemm1: g1 = gelu(x @ W1^T) -> bf16  (after topk: overwrites lnb/alpha region)
    dim3 g1d(N_TOK / 128, HDIM / 128);
    mfma_gemm<1><<<g1d, 256, 0, stream>>>(xb, w1b, nullptr, (void*)g1, N_TOK, HDIM, DDIM);

    // gemm2: out += g1 @ W2^T
    dim3 g2d(N_TOK / 128, DDIM / 128);
    mfma_gemm<2><<<g2d, 256, 0, stream>>>(g1, w2b, nullptr, (void*)out, N_TOK, DDIM, HDIM);
}

// Round 4
// 405.782 us; speedup vs baseline: 7.3917x; 1.4413x over previous
//
#include <hip/hip_runtime.h>
#include <hip/hip_bf16.h>
#include <math.h>

#define N_TOK 8192
#define DDIM  1024
#define HDIM  4096
#define NBLK  512

typedef __bf16 bf16x8 __attribute__((ext_vector_type(8)));
typedef __bf16 bf16x4 __attribute__((ext_vector_type(4)));
typedef float  floatx4 __attribute__((ext_vector_type(4)));

__device__ __forceinline__ float wave_reduce_sum(float v) {
#pragma unroll
    for (int off = 32; off > 0; off >>= 1) v += __shfl_down(v, off, 64);
    return v;
}

__device__ __forceinline__ void gload_lds16(const void* g, void* l) {
    __builtin_amdgcn_global_load_lds((const __attribute__((address_space(1))) void*)g,
                                     (__attribute__((address_space(3))) void*)l,
                                     16, 0, 0);
}

// Branchless gelu(x) = 0.5x(1+erf(x/sqrt2)); erf via A&S 7.1.26 (max err 1.5e-7).
// ~13 VALU ops vs libm erff's branchy ~35+.
__device__ __forceinline__ float fast_gelu(float x) {
    float ax = fabsf(x);
    float z  = ax * 0.70710678118654752f;
    float t  = __builtin_amdgcn_rcpf(fmaf(0.3275911f, z, 1.0f));
    float p  = fmaf(fmaf(fmaf(fmaf(1.061405429f, t, -1.453152027f),
                              t, 1.421413741f),
                         t, -0.284496736f),
                    t, 0.254829592f);
    p *= t;
    float e = __expf(-z * z);
    float E = fmaf(-p, e, 1.0f);      // erf(z), z>=0
    return 0.5f * fmaf(ax, E, x);     // 0.5*(x + |x|*erf)
}

__device__ __forceinline__ float fast_softplus(float r) {
    // r pre-clipped to [-10,10]: 1+e^r in [1.0000454, 22027.5], safe.
    return __logf(fmaf(1.0f, __expf(r), 1.0f));
}

// ---------------------------------------------------------------------------
// Fused prep kernel, 256 threads/block:
//  blocks [0,1024)        : normalize raw_U/raw_V rows -> unitU/unitV (fp32)
//  blocks [1024,9216)     : LayerNorm row -> lnb (bf16) AND cast x row -> xb
//  blocks [9216,13312)    : cast W1 -> w1b   (1024 elems/block)
//  blocks [13312,17408)   : cast W2 -> w2b
//  blocks [17408,17920)   : cast router_W -> rwb
// ---------------------------------------------------------------------------
__device__ __forceinline__ void cast1024(const float* __restrict__ s,
                                         __bf16* __restrict__ d,
                                         size_t off, int t) {
    float4 v = ((const float4*)(s + off))[t];
    bf16x4 o;
    o.x = (__bf16)v.x; o.y = (__bf16)v.y;
    o.z = (__bf16)v.z; o.w = (__bf16)v.w;
    ((bf16x4*)(d + off))[t] = o;
}

__global__ __launch_bounds__(256) void prep_kernel(
        const float* __restrict__ x,
        const float* __restrict__ ln_g, const float* __restrict__ ln_b,
        const float* __restrict__ W1,   const float* __restrict__ W2,
        const float* __restrict__ router_W,
        const float* __restrict__ rawU, const float* __restrict__ rawV,
        __bf16* __restrict__ xb,  __bf16* __restrict__ lnb,
        __bf16* __restrict__ w1b, __bf16* __restrict__ w2b,
        __bf16* __restrict__ rwb,
        float* __restrict__ unitU, float* __restrict__ unitV) {
    int b = blockIdx.x;
    int t = threadIdx.x;

    if (b < 1024) {                       // ---- unit rows of raw_U / raw_V
        const float* src = (b < NBLK) ? rawU + (size_t)b * DDIM
                                      : rawV + (size_t)(b - NBLK) * DDIM;
        float* dst = (b < NBLK) ? unitU + (size_t)b * DDIM
                                : unitV + (size_t)(b - NBLK) * DDIM;
        float vals[4];
        float ss = 0.f;
#pragma unroll
        for (int i = 0; i < 4; i++) { vals[i] = src[t + i * 256]; ss += vals[i] * vals[i]; }
        __shared__ float red[4];
        ss = wave_reduce_sum(ss);
        if ((t & 63) == 0) red[t >> 6] = ss;
        __syncthreads();
        float tot = red[0] + red[1] + red[2] + red[3];
        float inv = 1.f / fmaxf(sqrtf(tot), 1e-6f);
#pragma unroll
        for (int i = 0; i < 4; i++) dst[t + i * 256] = vals[i] * inv;
    } else if (b < 9216) {                // ---- LayerNorm + x cast
        int n = b - 1024;
        const float* row = x + (size_t)n * DDIM;
        float v[4];
        float s1 = 0.f, s2 = 0.f;
#pragma unroll
        for (int i = 0; i < 4; i++) {
            v[i] = row[t + i * 256];
            s1 += v[i];
            s2 += v[i] * v[i];
        }
        __shared__ float r1[4], r2[4];
        s1 = wave_reduce_sum(s1);
        s2 = wave_reduce_sum(s2);
        if ((t & 63) == 0) { r1[t >> 6] = s1; r2[t >> 6] = s2; }
        __syncthreads();
        float mu  = (r1[0] + r1[1] + r1[2] + r1[3]) * (1.f / DDIM);
        float var = (r2[0] + r2[1] + r2[2] + r2[3]) * (1.f / DDIM) - mu * mu;
        float rstd = rsqrtf(var + 1e-5f);
        __bf16* orow = lnb + (size_t)n * DDIM;
        __bf16* xrow = xb  + (size_t)n * DDIM;
#pragma unroll
        for (int i = 0; i < 4; i++) {
            int d = t + i * 256;
            orow[d] = (__bf16)((v[i] - mu) * rstd * ln_g[d] + ln_b[d]);
            xrow[d] = (__bf16)v[i];
        }
    } else if (b < 13312) {               // ---- W1 cast
        cast1024(W1, w1b, (size_t)(b - 9216) * 1024, t);
    } else if (b < 17408) {               // ---- W2 cast
        cast1024(W2, w2b, (size_t)(b - 13312) * 1024, t);
    } else {                              // ---- router_W cast
        cast1024(router_W, rwb, (size_t)(b - 17408) * 1024, t);
    }
}

// ---------------------------------------------------------------------------
// bf16 MFMA NT GEMM: C[M,Nn] = A[M,Kk] (bf16) * B[Nn,Kk]^T (bf16)
// 128x128 tile, BK=32, 256 threads (4 waves, 2x2 of 64x64), 16x16x32 MFMA.
// MODE 0: D = fast_softplus(clip(acc+bias)) -> fp32   (router)
// MODE 1: D = fast_gelu(acc) -> bf16                  (gemm1)
// MODE 2: C += acc (fp32 rmw)                         (gemm2)
// ---------------------------------------------------------------------------
template <int MODE>
__global__ __launch_bounds__(256) void mfma_gemm(const __bf16* __restrict__ A,
                                                 const __bf16* __restrict__ B,
                                                 const float* __restrict__ bias,
                                                 void* __restrict__ Cv,
                                                 int M, int Nn, int Kk) {
    __shared__ __align__(16) __bf16 As[128 * 32];
    __shared__ __align__(16) __bf16 Bs[128 * 32];

    const int t    = threadIdx.x;
    const int lane = t & 63;
    const int wave = t >> 6;
    const int wm   = wave >> 1, wn = wave & 1;
    const int lr   = lane & 15, quad = lane >> 4;
    const int m0   = blockIdx.x * 128;
    const int n0   = blockIdx.y * 128;

    const int ma0 = t >> 2,         ca0 = t & 3;
    const int ma1 = (256 + t) >> 2;
    const __bf16* Ag0 = A + (size_t)(m0 + ma0) * Kk + ca0 * 8;
    const __bf16* Ag1 = A + (size_t)(m0 + ma1) * Kk + ca0 * 8;
    const __bf16* Bg0 = B + (size_t)(n0 + ma0) * Kk + ca0 * 8;
    const __bf16* Bg1 = B + (size_t)(n0 + ma1) * Kk + ca0 * 8;
    __bf16* ldsA0 = As + t * 8;
    __bf16* ldsA1 = As + (256 + t) * 8;
    __bf16* ldsB0 = Bs + t * 8;
    __bf16* ldsB1 = Bs + (256 + t) * 8;

    const __bf16* ra[4];
    const __bf16* rb[4];
#pragma unroll
    for (int i = 0; i < 4; i++) {
        ra[i] = As + (wm * 64 + i * 16 + lr) * 32 + quad * 8;
        rb[i] = Bs + (wn * 64 + i * 16 + lr) * 32 + quad * 8;
    }

    floatx4 acc[4][4];
#pragma unroll
    for (int i = 0; i < 4; i++)
#pragma unroll
        for (int j = 0; j < 4; j++) acc[i][j] = (floatx4)0.f;

    for (int k0 = 0; k0 < Kk; k0 += 32) {
        gload_lds16(Ag0 + k0, ldsA0);
        gload_lds16(Ag1 + k0, ldsA1);
        gload_lds16(Bg0 + k0, ldsB0);
        gload_lds16(Bg1 + k0, ldsB1);
        __syncthreads();

        bf16x8 af[4], bfr[4];
#pragma unroll
        for (int i = 0; i < 4; i++) af[i]  = *(const bf16x8*)ra[i];
#pragma unroll
        for (int j = 0; j < 4; j++) bfr[j] = *(const bf16x8*)rb[j];
#pragma unroll
        for (int i = 0; i < 4; i++)
#pragma unroll
            for (int j = 0; j < 4; j++)
                acc[i][j] = __builtin_amdgcn_mfma_f32_16x16x32_bf16(af[i], bfr[j],
                                                                    acc[i][j], 0, 0, 0);
        __syncthreads();
    }

    const int mBase = m0 + wm * 64 + quad * 4;
    const int nBase = n0 + wn * 64 + lr;
#pragma unroll
    for (int i = 0; i < 4; i++) {
#pragma unroll
        for (int j = 0; j < 4; j++) {
            int n = nBase + j * 16;
#pragma unroll
            for (int r = 0; r < 4; r++) {
                int m = mBase + i * 16 + r;
                float v = acc[i][j][r];
                if (MODE == 0) {
                    float rr = v + bias[n];
                    rr = fminf(fmaxf(rr, -10.f), 10.f);
                    ((float*)Cv)[(size_t)m * Nn + n] = fast_softplus(rr);
                } else if (MODE == 1) {
                    ((__bf16*)Cv)[(size_t)m * Nn + n] = (__bf16)fast_gelu(v);
                } else {
                    ((float*)Cv)[(size_t)m * Nn + n] += v;
                }
            }
        }
    }
}

// ---------------------------------------------------------------------------
// Fused top-8 + dynamic path: one block (256 thr) per token.
// Wave 0 does the top-8 over alpha[n,:512]; then all 4 waves do the dyn math.
// Overwrites out.
// ---------------------------------------------------------------------------
__global__ __launch_bounds__(256) void topk_dyn_kernel(
        const float* __restrict__ alpha,
        const float* __restrict__ x,
        const float* __restrict__ unitU,
        const float* __restrict__ unitV,
        const float* __restrict__ gamma,
        float* __restrict__ out) {
    int n = blockIdx.x;
    int t = threadIdx.x;
    int lane = t & 63, wid = t >> 6;

    __shared__ int   sidx[8];
    __shared__ float shz[8];
    __shared__ float red[8][4];
    __shared__ float hz[8];

    if (wid == 0) {  // wave-local top-8 over 512 values, 8 per lane
        const float* row = alpha + (size_t)n * NBLK;
        float v[8];
#pragma unroll
        for (int i = 0; i < 8; i++) v[i] = row[lane + i * 64];
        float topv[8];
        int   topi[8];
        for (int s = 0; s < 8; s++) {
            float bv = v[0]; int bi = 0;
#pragma unroll
            for (int i = 1; i < 8; i++)
                if (v[i] > bv) { bv = v[i]; bi = i; }
            int gidx = lane + bi * 64;
#pragma unroll
            for (int off = 1; off < 64; off <<= 1) {
                float ov = __shfl_xor(bv, off, 64);
                int   oi = __shfl_xor(gidx, off, 64);
                if (ov > bv || (ov == bv && oi < gidx)) { bv = ov; gidx = oi; }
            }
            topv[s] = bv; topi[s] = gidx;
            if ((gidx & 63) == lane) v[gidx >> 6] = -1e30f;
        }
        float S = 0.f;
#pragma unroll
        for (int s = 0; s < 8; s++) S += topv[s];
        float zscale = tanhf(S) / (S + 1e-6f);
        if (lane < 8) {
            sidx[lane] = topi[lane];
            shz[lane]  = topv[lane] * zscale;
        }
    }
    __syncthreads();

    const float* xr = x + (size_t)n * DDIM;
    float xv[4];
#pragma unroll
    for (int i = 0; i < 4; i++) xv[i] = xr[t + i * 256];

    float acc[8];
#pragma unroll
    for (int k = 0; k < 8; k++) {
        const float* ur = unitU + (size_t)sidx[k] * DDIM;
        float a = 0.f;
#pragma unroll
        for (int i = 0; i < 4; i++) a = fmaf(xv[i], ur[t + i * 256], a);
        acc[k] = a;
    }
#pragma unroll
    for (int k = 0; k < 8; k++) {
        float a = wave_reduce_sum(acc[k]);
        if (lane == 0) red[k][wid] = a;
    }
    __syncthreads();
    if (t < 8) {
        float h = red[t][0] + red[t][1] + red[t][2] + red[t][3];
        hz[t] = h * shz[t];
    }
    __syncthreads();

    float* orow = out + (size_t)n * DDIM;
#pragma unroll
    for (int i = 0; i < 4; i++) {
        int d = t + i * 256;
        float s = 0.f;
#pragma unroll
        for (int k = 0; k < 8; k++)
            s = fmaf(hz[k], unitV[(size_t)sidx[k] * DDIM + d], s);
        orow[d] = s * gamma[d];
    }
}

// ---------------------------------------------------------------------------
extern "C" void kernel_launch(void* const* d_in, const int* in_sizes, int n_in,
                              void* d_out, int out_size, void* d_ws, size_t ws_size,
                              hipStream_t stream) {
    const float* x        = (const float*)d_in[0];
    const float* W1       = (const float*)d_in[1];
    const float* W2       = (const float*)d_in[2];
    const float* ln_g     = (const float*)d_in[3];
    const float* ln_b     = (const float*)d_in[4];
    const float* router_W = (const float*)d_in[5];
    const float* router_b = (const float*)d_in[6];
    const float* raw_U    = (const float*)d_in[7];
    const float* raw_V    = (const float*)d_in[8];
    const float* gamma    = (const float*)d_in[9];
    float* out = (float*)d_out;

    char* ws = (char*)d_ws;
    // region [0, 67.1MB): lnb+alpha early, g1 later (dead/live ranges disjoint)
    __bf16* lnb   = (__bf16*)(ws);                 // 16,777,216 B
    float*  alpha = (float*)(ws + 16777216u);      // 16,777,216 B
    __bf16* g1    = (__bf16*)(ws);                 // 67,108,864 B (after topk_dyn)
    __bf16* xb    = (__bf16*)(ws + 67108864u);     // 16,777,216 B
    __bf16* w1b   = (__bf16*)(ws + 83886080u);     //  8,388,608 B
    __bf16* w2b   = (__bf16*)(ws + 92274688u);     //  8,388,608 B
    __bf16* rwb   = (__bf16*)(ws + 100663296u);    //  1,048,576 B
    float*  unitU = (float*)(ws + 101711872u);     //  2,097,152 B
    float*  unitV = (float*)(ws + 103809024u);     //  2,097,152 B
    // total ws use: 105,906,176 B

    // one fused prep launch: unit rows, LN(+x cast), W1/W2/router casts
    prep_kernel<<<17920, 256, 0, stream>>>(x, ln_g, ln_b, W1, W2, router_W,
                                           raw_U, raw_V, xb, lnb, w1b, w2b, rwb,
                                           unitU, unitV);

    // router: [8192,512] = lnb @ rwb^T, softplus epilogue
    dim3 gR(N_TOK / 128, NBLK / 128);
    mfma_gemm<0><<<gR, 256, 0, stream>>>(lnb, rwb, router_b, (void*)alpha, N_TOK, NBLK, DDIM);

    // fused top-8 + dynamic path (overwrites out)
    topk_dyn_kernel<<<N_TOK, 256, 0, stream>>>(alpha, x, unitU, unitV, gamma, out);

    // gemm1: g1 = gelu(x @ W1^T) -> bf16  (after topk_dyn: reuses lnb/alpha region)
    dim3 g1d(N_TOK / 128, HDIM / 128);
    mfma_gemm<1><<<g1d, 256, 0, stream>>>(xb, w1b, nullptr, (void*)g1, N_TOK, HDIM, DDIM);

    // gemm2: out += g1 @ W2^T
    dim3 g2d(N_TOK / 128, DDIM / 128);
    mfma_gemm<2><<<g2d, 256, 0, stream>>>(g1, w2b, nullptr, (void*)out, N_TOK, DDIM, HDIM);
}